// Round 5
// baseline (167.569 us; speedup 1.0000x reference)
//
#include <hip/hip_runtime.h>

// Fused 3-layer MLP via MFMA with split-bf16 (hi+lo) 3-term products:
//   out = relu(relu(x@W0+b0)@W1+b1)@W2+b2
// x: [N,128] f32, W0:[128,32], W1:[32,32], W2:[32,16], out:[N,16] f32.
// edge_index/edge_weight unused (ChebConv K=1).
//
// R5 structure:
//  - single kernel: weight hi/lo fragments computed during per-block LDS
//    staging (no separate split_weights launch, d_ws unused)
//  - software-pipelined x reads: prefetch tile t+1's 8 float4s into
//    registers while computing tile t (loads continuously in flight)
//  - output stored as one global_store_dwordx4 per tile via wave-private
//    LDS f32 transpose (1KB contiguous)
//  - persistent grid, 4 blocks/CU, barrier-free main loop
//
// MFMA frag layouts (m89-verified):
//  A: lane l holds A[l&15][8*(l>>4)+j], j=0..7
//  B: lane l holds B[8*(l>>4)+j][l&15]
//  C/D: lane l holds D[4*(l>>4)+i][l&15], i=0..3
// Split: v = hi + lo, hi = trunc-to-bf16 (bit mask, exact),
// lo = rne-bf16(v - hi); product = ah*bh + al*bh + ah*bl (~f32 accuracy).

#define N_IN  128
#define HID   32
#define N_OUT 16

using f32x4  = __attribute__((ext_vector_type(4))) float;
using short8 = __attribute__((ext_vector_type(8))) short;
using uint4v = __attribute__((ext_vector_type(4))) unsigned int;

// chunk layout in wlds (each chunk = 64 lanes * 8 bf16 = 512 shorts = 1KB):
//  W0: chunks [0,16): chunk = kc*4 + nh*2 + hl   (kc=0..3, nh=0..1, hl=0..1)
//  W1: chunks [16,20): 16 + nh*2 + hl
//  W2: chunks [20,22): 20 + hl
#define N_CHUNKS 22

__device__ __forceinline__ unsigned fu(float f) {
    union { float f; unsigned u; } v; v.f = f; return v.u;
}
__device__ __forceinline__ float uf(unsigned u) {
    union { unsigned u; float f; } v; v.u = u; return v.f;
}
__device__ __forceinline__ unsigned short f2bf_rne(float f) {
    unsigned u = fu(f);
    return (unsigned short)((u + 0x7fffu + ((u >> 16) & 1u)) >> 16);
}

#define MFMA3(acc, ah, al, bh, bl)                                          \
    do {                                                                    \
        acc = __builtin_amdgcn_mfma_f32_16x16x32_bf16(ah, bh, acc, 0, 0, 0);\
        acc = __builtin_amdgcn_mfma_f32_16x16x32_bf16(al, bh, acc, 0, 0, 0);\
        acc = __builtin_amdgcn_mfma_f32_16x16x32_bf16(ah, bl, acc, 0, 0, 0);\
    } while (0)

__global__ __launch_bounds__(256, 4) void gnn_mfma(
    const float* __restrict__ x,
    const float* __restrict__ W0, const float* __restrict__ b0,
    const float* __restrict__ W1, const float* __restrict__ b1,
    const float* __restrict__ W2, const float* __restrict__ b2,
    float* __restrict__ out, int n_tiles, int stride)
{
    __shared__ __align__(16) unsigned short wlds[N_CHUNKS * 512];  // 22 KB
    // wave-private bf16 transpose buffer: [wave][hl][row 16][col 32 + pad 8]
    __shared__ __align__(16) unsigned short hbuf[4][2][16][40];    // 10.25 KB
    // wave-private f32 store-transpose buffer: [wave][row 16][col 16 + pad 4]
    __shared__ __align__(16) float sbuf[4][16][20];                // 5 KB

    const int tid  = threadIdx.x;
    const int wave = tid >> 6;
    const int l    = tid & 63;
    const int r16  = l & 15;
    const int g    = l >> 4;

    // ---- compute weight hi/lo fragments directly into LDS (once per block) ----
    for (int c = wave; c < N_CHUNKS; c += 4) {
        const float* W; int ncol, kbase, col, hl;
        if (c < 16) {
            int kc = c >> 2, nh = (c >> 1) & 1; hl = c & 1;
            W = W0; ncol = HID; kbase = kc * 32 + 8 * (l >> 4); col = nh * 16 + (l & 15);
        } else if (c < 20) {
            int c2 = c - 16, nh = c2 >> 1; hl = c2 & 1;
            W = W1; ncol = HID; kbase = 8 * (l >> 4); col = nh * 16 + (l & 15);
        } else {
            hl = c - 20;
            W = W2; ncol = N_OUT; kbase = 8 * (l >> 4); col = l & 15;
        }
        unsigned short tmp[8];
        #pragma unroll
        for (int j = 0; j < 8; ++j) {
            float v = W[(kbase + j) * ncol + col];
            unsigned hb = fu(v) & 0xFFFF0000u;
            tmp[j] = (hl == 0) ? (unsigned short)(hb >> 16)
                               : f2bf_rne(v - uf(hb));
        }
        *reinterpret_cast<short8*>(&wlds[c * 512 + l * 8]) =
            *reinterpret_cast<const short8*>(tmp);
    }
    __syncthreads();   // the only block-wide barrier

    const short8* WL = reinterpret_cast<const short8*>(wlds);

    const float bc0a = b0[r16], bc0b = b0[16 + r16];
    const float bc1a = b1[r16], bc1b = b1[16 + r16];
    const float bc2  = b2[r16];

    const int gw = blockIdx.x * 4 + wave;   // global wave id
    if (gw >= n_tiles) return;

    // ---- prologue: issue first tile's x loads ----
    float4 cur[8];
    {
        const float* xr = x + (size_t)(gw * 16 + r16) * N_IN + g * 8;
        #pragma unroll
        for (int kc = 0; kc < 4; ++kc) {
            cur[2 * kc]     = *reinterpret_cast<const float4*>(xr + kc * 32);
            cur[2 * kc + 1] = *reinterpret_cast<const float4*>(xr + kc * 32 + 4);
        }
    }

    for (int tile = gw; tile < n_tiles; tile += stride) {
        // ---- issue next tile's loads (clamped on last iter; L1-hot) ----
        int nt = tile + stride;
        int pft = (nt < n_tiles) ? nt : tile;
        float4 nxt[8];
        {
            const float* xr = x + (size_t)(pft * 16 + r16) * N_IN + g * 8;
            #pragma unroll
            for (int kc = 0; kc < 4; ++kc) {
                nxt[2 * kc]     = *reinterpret_cast<const float4*>(xr + kc * 32);
                nxt[2 * kc + 1] = *reinterpret_cast<const float4*>(xr + kc * 32 + 4);
            }
        }

        const int nb = tile * 16;

        // -------- layer 0: h0 = relu(x @ W0 + b0), K=128 --------
        f32x4 acc0 = {0.f, 0.f, 0.f, 0.f};
        f32x4 acc1 = {0.f, 0.f, 0.f, 0.f};

        #pragma unroll
        for (int kc = 0; kc < 4; ++kc) {
            float4 xa = cur[2 * kc];
            float4 xb = cur[2 * kc + 1];
            float f[8] = {xa.x, xa.y, xa.z, xa.w, xb.x, xb.y, xb.z, xb.w};
            uint4v hv, lv;
            #pragma unroll
            for (int p = 0; p < 4; ++p) {
                unsigned u0 = fu(f[2 * p]), u1 = fu(f[2 * p + 1]);
                unsigned h0b = u0 & 0xFFFF0000u, h1b = u1 & 0xFFFF0000u;
                hv[p] = h1b | (u0 >> 16);
                float l0 = f[2 * p] - uf(h0b), l1 = f[2 * p + 1] - uf(h1b);
                lv[p] = (fu(l1) & 0xFFFF0000u) | (fu(l0) >> 16);
            }
            short8 ah = __builtin_bit_cast(short8, hv);
            short8 al = __builtin_bit_cast(short8, lv);
            short8 w0h0 = WL[(kc * 4 + 0) * 64 + l];
            short8 w0l0 = WL[(kc * 4 + 1) * 64 + l];
            short8 w0h1 = WL[(kc * 4 + 2) * 64 + l];
            short8 w0l1 = WL[(kc * 4 + 3) * 64 + l];
            MFMA3(acc0, ah, al, w0h0, w0l0);
            MFMA3(acc1, ah, al, w0h1, w0l1);
        }

        // bias + relu, split hi/lo, wave-private LDS transpose (no barrier)
        #pragma unroll
        for (int i = 0; i < 4; ++i) {
            int row = 4 * g + i;
            float h = fmaxf(acc0[i] + bc0a, 0.f);
            unsigned hb = fu(h) & 0xFFFF0000u;
            hbuf[wave][0][row][r16] = (unsigned short)(hb >> 16);
            hbuf[wave][1][row][r16] = (unsigned short)(fu(h - uf(hb)) >> 16);
            float h2 = fmaxf(acc1[i] + bc0b, 0.f);
            unsigned hb2 = fu(h2) & 0xFFFF0000u;
            hbuf[wave][0][row][16 + r16] = (unsigned short)(hb2 >> 16);
            hbuf[wave][1][row][16 + r16] = (unsigned short)(fu(h2 - uf(hb2)) >> 16);
        }
        short8 h0h = *reinterpret_cast<const short8*>(&hbuf[wave][0][r16][g * 8]);
        short8 h0l = *reinterpret_cast<const short8*>(&hbuf[wave][1][r16][g * 8]);

        // -------- layer 1: h1 = relu(h0 @ W1 + b1), K=32 --------
        f32x4 acc2 = {0.f, 0.f, 0.f, 0.f};
        f32x4 acc3 = {0.f, 0.f, 0.f, 0.f};
        {
            short8 w1h0 = WL[(16 + 0) * 64 + l];
            short8 w1l0 = WL[(16 + 1) * 64 + l];
            short8 w1h1 = WL[(16 + 2) * 64 + l];
            short8 w1l1 = WL[(16 + 3) * 64 + l];
            MFMA3(acc2, h0h, h0l, w1h0, w1l0);
            MFMA3(acc3, h0h, h0l, w1h1, w1l1);
        }
        #pragma unroll
        for (int i = 0; i < 4; ++i) {
            int row = 4 * g + i;
            float h = fmaxf(acc2[i] + bc1a, 0.f);
            unsigned hb = fu(h) & 0xFFFF0000u;
            hbuf[wave][0][row][r16] = (unsigned short)(hb >> 16);
            hbuf[wave][1][row][r16] = (unsigned short)(fu(h - uf(hb)) >> 16);
            float h2 = fmaxf(acc3[i] + bc1b, 0.f);
            unsigned hb2 = fu(h2) & 0xFFFF0000u;
            hbuf[wave][0][row][16 + r16] = (unsigned short)(hb2 >> 16);
            hbuf[wave][1][row][16 + r16] = (unsigned short)(fu(h2 - uf(hb2)) >> 16);
        }
        short8 h1h = *reinterpret_cast<const short8*>(&hbuf[wave][0][r16][g * 8]);
        short8 h1l = *reinterpret_cast<const short8*>(&hbuf[wave][1][r16][g * 8]);

        // -------- layer 2: o = h1 @ W2 + b2, K=32, N=16 --------
        f32x4 accO = {0.f, 0.f, 0.f, 0.f};
        {
            short8 w2h = WL[(20) * 64 + l];
            short8 w2l = WL[(21) * 64 + l];
            MFMA3(accO, h1h, h1l, w2h, w2l);
        }

        // f32 transpose via wave-private LDS, then one dwordx4 store
        #pragma unroll
        for (int i = 0; i < 4; ++i)
            sbuf[wave][4 * g + i][r16] = accO[i] + bc2;
        f32x4 ov = *reinterpret_cast<const f32x4*>(&sbuf[wave][l >> 2][(l & 3) * 4]);
        *reinterpret_cast<f32x4*>(out + (size_t)(nb + (l >> 2)) * N_OUT + (l & 3) * 4) = ov;

        // rotate prefetched registers
        #pragma unroll
        for (int q = 0; q < 8; ++q) cur[q] = nxt[q];
    }
}

extern "C" void kernel_launch(void* const* d_in, const int* in_sizes, int n_in,
                              void* d_out, int out_size, void* d_ws, size_t ws_size,
                              hipStream_t stream) {
    // setup_inputs() order: x, edge_index, edge_weight, W0, b0, W1, b1, W2, b2
    const float* x  = (const float*)d_in[0];
    const float* W0 = (const float*)d_in[3];
    const float* b0 = (const float*)d_in[4];
    const float* W1 = (const float*)d_in[5];
    const float* b1 = (const float*)d_in[6];
    const float* W2 = (const float*)d_in[7];
    const float* b2 = (const float*)d_in[8];
    float* out = (float*)d_out;

    int n_nodes = in_sizes[0] / N_IN;             // 1,000,000
    int n_tiles = n_nodes / 16;                   // 62,500 (exact)

    const int n_blocks = 1024;                    // 4 blocks/CU persistent
    const int n_waves_total = n_blocks * 4;
    gnn_mfma<<<dim3(n_blocks), dim3(256), 0, stream>>>(
        x, W0, b0, W1, b1, W2, b2, out, n_tiles, n_waves_total);
}

// Round 6
// 134.484 us; speedup vs baseline: 1.2460x; 1.2460x over previous
//
#include <hip/hip_runtime.h>

// Fused 3-layer MLP via MFMA with split-bf16 (hi+lo) 3-term products:
//   out = relu(relu(x@W0+b0)@W1+b1)@W2+b2
// x: [N,128] f32, W0:[128,32], W1:[32,32], W2:[32,16], out:[N,16] f32.
// edge_index/edge_weight unused (ChebConv K=1).
//
// R6 = R4 structure + two attributable changes:
//  1. weight hi/lo fragments computed in-kernel during LDS staging
//     (no separate split_weights dispatch; numerically identical, R5-proven)
//  2. HALF-tile x prefetch: per tile, issue kc2/3 loads at tile start,
//     compute kc0/1, then issue NEXT tile's kc0/1 loads before layers 1/2 +
//     store. Only +16 VGPRs (R5's full prefetch = +64 -> spills -> 167us).
//     Staggers VMEM issue to kill the lockstep HBM-idle windows.
//
// MFMA frag layouts (m89-verified):
//  A: lane l holds A[l&15][8*(l>>4)+j], j=0..7
//  B: lane l holds B[8*(l>>4)+j][l&15]
//  C/D: lane l holds D[4*(l>>4)+i][l&15], i=0..3
// Split: v = hi + lo, hi = trunc-to-bf16 (bit mask, exact),
// lo = rne-bf16(v - hi); product = ah*bh + al*bh + ah*bl (~f32 accuracy).

#define N_IN  128
#define HID   32
#define N_OUT 16

using f32x4  = __attribute__((ext_vector_type(4))) float;
using short8 = __attribute__((ext_vector_type(8))) short;
using uint4v = __attribute__((ext_vector_type(4))) unsigned int;

// chunk layout in wlds (each chunk = 64 lanes * 8 bf16 = 512 shorts = 1KB):
//  W0: chunks [0,16): chunk = kc*4 + nh*2 + hl   (kc=0..3, nh=0..1, hl=0..1)
//  W1: chunks [16,20): 16 + nh*2 + hl
//  W2: chunks [20,22): 20 + hl
#define N_CHUNKS 22

__device__ __forceinline__ unsigned fu(float f) {
    union { float f; unsigned u; } v; v.f = f; return v.u;
}
__device__ __forceinline__ float uf(unsigned u) {
    union { unsigned u; float f; } v; v.u = u; return v.f;
}
__device__ __forceinline__ unsigned short f2bf_rne(float f) {
    unsigned u = fu(f);
    return (unsigned short)((u + 0x7fffu + ((u >> 16) & 1u)) >> 16);
}

#define MFMA3(acc, ah, al, bh, bl)                                          \
    do {                                                                    \
        acc = __builtin_amdgcn_mfma_f32_16x16x32_bf16(ah, bh, acc, 0, 0, 0);\
        acc = __builtin_amdgcn_mfma_f32_16x16x32_bf16(al, bh, acc, 0, 0, 0);\
        acc = __builtin_amdgcn_mfma_f32_16x16x32_bf16(ah, bl, acc, 0, 0, 0);\
    } while (0)

__global__ __launch_bounds__(256, 4) void gnn_mfma(
    const float* __restrict__ x,
    const float* __restrict__ W0, const float* __restrict__ b0,
    const float* __restrict__ W1, const float* __restrict__ b1,
    const float* __restrict__ W2, const float* __restrict__ b2,
    float* __restrict__ out, int n_tiles, int stride)
{
    __shared__ __align__(16) unsigned short wlds[N_CHUNKS * 512];  // 22 KB
    // wave-private bf16 transpose buffer: [wave][hl][row 16][col 32 + pad 8]
    __shared__ __align__(16) unsigned short hbuf[4][2][16][40];    // 10.25 KB

    const int tid  = threadIdx.x;
    const int wave = tid >> 6;
    const int l    = tid & 63;
    const int r16  = l & 15;
    const int g    = l >> 4;

    // ---- compute weight hi/lo fragments directly into LDS (once per block) ----
    for (int c = wave; c < N_CHUNKS; c += 4) {
        const float* W; int ncol, kbase, col, hl;
        if (c < 16) {
            int kc = c >> 2, nh = (c >> 1) & 1; hl = c & 1;
            W = W0; ncol = HID; kbase = kc * 32 + 8 * (l >> 4); col = nh * 16 + (l & 15);
        } else if (c < 20) {
            int c2 = c - 16, nh = c2 >> 1; hl = c2 & 1;
            W = W1; ncol = HID; kbase = 8 * (l >> 4); col = nh * 16 + (l & 15);
        } else {
            hl = c - 20;
            W = W2; ncol = N_OUT; kbase = 8 * (l >> 4); col = l & 15;
        }
        unsigned short tmp[8];
        #pragma unroll
        for (int j = 0; j < 8; ++j) {
            float v = W[(kbase + j) * ncol + col];
            unsigned hb = fu(v) & 0xFFFF0000u;
            tmp[j] = (hl == 0) ? (unsigned short)(hb >> 16)
                               : f2bf_rne(v - uf(hb));
        }
        *reinterpret_cast<short8*>(&wlds[c * 512 + l * 8]) =
            *reinterpret_cast<const short8*>(tmp);
    }
    __syncthreads();   // the only block-wide barrier

    const short8* WL = reinterpret_cast<const short8*>(wlds);

    const float bc0a = b0[r16], bc0b = b0[16 + r16];
    const float bc1a = b1[r16], bc1b = b1[16 + r16];
    const float bc2  = b2[r16];

    const int gw = blockIdx.x * 4 + wave;   // global wave id

    // ---- prologue: issue first tile's kc0/1 loads (half tile, 16 VGPRs) ----
    float4 curA[4];
    {
        const float* xr = x + (size_t)(gw * 16 + r16) * N_IN + g * 8;
        curA[0] = *reinterpret_cast<const float4*>(xr);
        curA[1] = *reinterpret_cast<const float4*>(xr + 4);
        curA[2] = *reinterpret_cast<const float4*>(xr + 32);
        curA[3] = *reinterpret_cast<const float4*>(xr + 36);
    }

    for (int tile = gw; tile < n_tiles; tile += stride) {
        const int nb = tile * 16;
        const float* xr = x + (size_t)(nb + r16) * N_IN + g * 8;

        // ---- issue this tile's kc2/3 loads ----
        float4 curB[4];
        curB[0] = *reinterpret_cast<const float4*>(xr + 64);
        curB[1] = *reinterpret_cast<const float4*>(xr + 68);
        curB[2] = *reinterpret_cast<const float4*>(xr + 96);
        curB[3] = *reinterpret_cast<const float4*>(xr + 100);

        f32x4 acc0 = {0.f, 0.f, 0.f, 0.f};
        f32x4 acc1 = {0.f, 0.f, 0.f, 0.f};

        // process one kc chunk (8 floats) -> split -> 6 MFMAs
        #define PROC(kc, xa, xb)                                               \
        do {                                                                   \
            float f[8] = {(xa).x, (xa).y, (xa).z, (xa).w,                      \
                          (xb).x, (xb).y, (xb).z, (xb).w};                     \
            uint4v hv, lv;                                                     \
            _Pragma("unroll")                                                  \
            for (int p = 0; p < 4; ++p) {                                      \
                unsigned u0 = fu(f[2 * p]), u1 = fu(f[2 * p + 1]);             \
                unsigned h0b = u0 & 0xFFFF0000u, h1b = u1 & 0xFFFF0000u;       \
                hv[p] = h1b | (u0 >> 16);                                      \
                float l0 = f[2 * p] - uf(h0b), l1 = f[2 * p + 1] - uf(h1b);    \
                lv[p] = (fu(l1) & 0xFFFF0000u) | (fu(l0) >> 16);               \
            }                                                                  \
            short8 ah = __builtin_bit_cast(short8, hv);                        \
            short8 al = __builtin_bit_cast(short8, lv);                        \
            short8 w0h0 = WL[((kc) * 4 + 0) * 64 + l];                         \
            short8 w0l0 = WL[((kc) * 4 + 1) * 64 + l];                         \
            short8 w0h1 = WL[((kc) * 4 + 2) * 64 + l];                         \
            short8 w0l1 = WL[((kc) * 4 + 3) * 64 + l];                         \
            MFMA3(acc0, ah, al, w0h0, w0l0);                                   \
            MFMA3(acc1, ah, al, w0h1, w0l1);                                   \
        } while (0)

        // compute kc0/1 from curA (curB still in flight)
        PROC(0, curA[0], curA[1]);
        PROC(1, curA[2], curA[3]);

        // ---- issue NEXT tile's kc0/1 loads (curA regs now dead) ----
        {
            int nt = tile + stride;
            int pf = (nt < n_tiles) ? nt : tile;
            const float* xn = x + (size_t)(pf * 16 + r16) * N_IN + g * 8;
            curA[0] = *reinterpret_cast<const float4*>(xn);
            curA[1] = *reinterpret_cast<const float4*>(xn + 4);
            curA[2] = *reinterpret_cast<const float4*>(xn + 32);
            curA[3] = *reinterpret_cast<const float4*>(xn + 36);
        }

        // compute kc2/3 from curB
        PROC(2, curB[0], curB[1]);
        PROC(3, curB[2], curB[3]);
        #undef PROC

        // bias + relu, split hi/lo, wave-private LDS transpose (no barrier)
        #pragma unroll
        for (int i = 0; i < 4; ++i) {
            int row = 4 * g + i;
            float h = fmaxf(acc0[i] + bc0a, 0.f);
            unsigned hb = fu(h) & 0xFFFF0000u;
            hbuf[wave][0][row][r16] = (unsigned short)(hb >> 16);
            hbuf[wave][1][row][r16] = (unsigned short)(fu(h - uf(hb)) >> 16);
            float h2 = fmaxf(acc1[i] + bc0b, 0.f);
            unsigned hb2 = fu(h2) & 0xFFFF0000u;
            hbuf[wave][0][row][16 + r16] = (unsigned short)(hb2 >> 16);
            hbuf[wave][1][row][16 + r16] = (unsigned short)(fu(h2 - uf(hb2)) >> 16);
        }
        short8 h0h = *reinterpret_cast<const short8*>(&hbuf[wave][0][r16][g * 8]);
        short8 h0l = *reinterpret_cast<const short8*>(&hbuf[wave][1][r16][g * 8]);

        // -------- layer 1: h1 = relu(h0 @ W1 + b1), K=32 --------
        f32x4 acc2 = {0.f, 0.f, 0.f, 0.f};
        f32x4 acc3 = {0.f, 0.f, 0.f, 0.f};
        {
            short8 w1h0 = WL[(16 + 0) * 64 + l];
            short8 w1l0 = WL[(16 + 1) * 64 + l];
            short8 w1h1 = WL[(16 + 2) * 64 + l];
            short8 w1l1 = WL[(16 + 3) * 64 + l];
            MFMA3(acc2, h0h, h0l, w1h0, w1l0);
            MFMA3(acc3, h0h, h0l, w1h1, w1l1);
        }
        #pragma unroll
        for (int i = 0; i < 4; ++i) {
            int row = 4 * g + i;
            float h = fmaxf(acc2[i] + bc1a, 0.f);
            unsigned hb = fu(h) & 0xFFFF0000u;
            hbuf[wave][0][row][r16] = (unsigned short)(hb >> 16);
            hbuf[wave][1][row][r16] = (unsigned short)(fu(h - uf(hb)) >> 16);
            float h2 = fmaxf(acc3[i] + bc1b, 0.f);
            unsigned hb2 = fu(h2) & 0xFFFF0000u;
            hbuf[wave][0][row][16 + r16] = (unsigned short)(hb2 >> 16);
            hbuf[wave][1][row][16 + r16] = (unsigned short)(fu(h2 - uf(hb2)) >> 16);
        }
        short8 h1h = *reinterpret_cast<const short8*>(&hbuf[wave][0][r16][g * 8]);
        short8 h1l = *reinterpret_cast<const short8*>(&hbuf[wave][1][r16][g * 8]);

        // -------- layer 2: o = h1 @ W2 + b2, K=32, N=16 --------
        f32x4 accO = {0.f, 0.f, 0.f, 0.f};
        {
            short8 w2h = WL[(20) * 64 + l];
            short8 w2l = WL[(21) * 64 + l];
            MFMA3(accO, h1h, h1l, w2h, w2l);
        }
        #pragma unroll
        for (int i = 0; i < 4; ++i) {
            int row = 4 * g + i;
            out[(size_t)(nb + row) * N_OUT + r16] = accO[i] + bc2;
        }
    }
}

extern "C" void kernel_launch(void* const* d_in, const int* in_sizes, int n_in,
                              void* d_out, int out_size, void* d_ws, size_t ws_size,
                              hipStream_t stream) {
    // setup_inputs() order: x, edge_index, edge_weight, W0, b0, W1, b1, W2, b2
    const float* x  = (const float*)d_in[0];
    const float* W0 = (const float*)d_in[3];
    const float* b0 = (const float*)d_in[4];
    const float* W1 = (const float*)d_in[5];
    const float* b1 = (const float*)d_in[6];
    const float* W2 = (const float*)d_in[7];
    const float* b2 = (const float*)d_in[8];
    float* out = (float*)d_out;

    int n_nodes = in_sizes[0] / N_IN;             // 1,000,000
    int n_tiles = n_nodes / 16;                   // 62,500 (exact)

    const int n_blocks = 1024;                    // 4 blocks/CU persistent
    const int n_waves_total = n_blocks * 4;
    gnn_mfma<<<dim3(n_blocks), dim3(256), 0, stream>>>(
        x, W0, b0, W1, b1, W2, b2, out, n_tiles, n_waves_total);
}

// Round 7
// 118.685 us; speedup vs baseline: 1.4119x; 1.1331x over previous
//
#include <hip/hip_runtime.h>

// Fused 3-layer MLP via MFMA with split-bf16 (hi+lo) 3-term products:
//   out = relu(relu(x@W0+b0)@W1+b1)@W2+b2
// x: [N,128] f32, W0:[128,32], W1:[32,32], W2:[32,16], out:[N,16] f32.
// edge_index/edge_weight unused (ChebConv K=1).
//
// R7 = R4 exact structure (known-good 118.4us: separate split_weights
// dispatch, burst x-loads at tile start, persistent grid 4 blocks/CU,
// barrier-free main loop, weights in LDS) + ONE change:
//   non-temporal loads for the x stream and non-temporal stores for out.
// x is read exactly once (no reuse) and out written once; nt bypasses
// L1 allocation -> frees the L1 miss-tracking path (each x-load touches
// 32 distinct 64B lines; the burst was MSHR-capped) and stops 512MB of
// stream from thrashing L2.
//
// MFMA frag layouts (m89-verified):
//  A: lane l holds A[l&15][8*(l>>4)+j], j=0..7
//  B: lane l holds B[8*(l>>4)+j][l&15]
//  C/D: lane l holds D[4*(l>>4)+i][l&15], i=0..3
// Split: v = hi + lo, hi = trunc-to-bf16 (bit mask, exact),
// lo = rne-bf16(v - hi); product = ah*bh + al*bh + ah*bl (~f32 accuracy).

#define N_IN  128
#define HID   32
#define N_OUT 16

using f32x4  = __attribute__((ext_vector_type(4))) float;
using short8 = __attribute__((ext_vector_type(8))) short;
using uint4v = __attribute__((ext_vector_type(4))) unsigned int;

// chunk layout in ws (each chunk = 64 lanes * 8 bf16 = 512 shorts = 1KB):
//  W0: chunks [0,16): chunk = kc*4 + nh*2 + hl   (kc=0..3, nh=0..1, hl=0..1)
//  W1: chunks [16,20): 16 + nh*2 + hl
//  W2: chunks [20,22): 20 + hl
#define N_CHUNKS 22
#define TOTAL_WF_SHORTS (N_CHUNKS * 512)
#define WLDS_GRANULES (N_CHUNKS * 64)   // 16B granules

__device__ __forceinline__ unsigned fu(float f) {
    union { float f; unsigned u; } v; v.f = f; return v.u;
}
__device__ __forceinline__ float uf(unsigned u) {
    union { unsigned u; float f; } v; v.u = u; return v.f;
}
__device__ __forceinline__ unsigned short f2bf_rne(float f) {
    unsigned u = fu(f);
    return (unsigned short)((u + 0x7fffu + ((u >> 16) & 1u)) >> 16);
}

__global__ void split_weights(const float* __restrict__ W0,
                              const float* __restrict__ W1,
                              const float* __restrict__ W2,
                              unsigned short* __restrict__ wf) {
    int idx = blockIdx.x * blockDim.x + threadIdx.x;
    if (idx >= TOTAL_WF_SHORTS) return;
    int chunk  = idx >> 9;
    int within = idx & 511;
    int lane = within >> 3;
    int j    = within & 7;
    const float* W; int ncol, k, col, hl;
    if (chunk < 16) {
        int kc = chunk >> 2, nh = (chunk >> 1) & 1; hl = chunk & 1;
        k = kc * 32 + 8 * (lane >> 4) + j; col = nh * 16 + (lane & 15);
        W = W0; ncol = HID;
    } else if (chunk < 20) {
        int c2 = chunk - 16, nh = c2 >> 1; hl = c2 & 1;
        k = 8 * (lane >> 4) + j; col = nh * 16 + (lane & 15);
        W = W1; ncol = HID;
    } else {
        hl = chunk - 20;
        k = 8 * (lane >> 4) + j; col = lane & 15;
        W = W2; ncol = N_OUT;
    }
    float v = W[k * ncol + col];
    unsigned hi_bits = fu(v) & 0xFFFF0000u;
    wf[idx] = (hl == 0) ? (unsigned short)(hi_bits >> 16)
                        : f2bf_rne(v - uf(hi_bits));
}

#define MFMA3(acc, ah, al, bh, bl)                                          \
    do {                                                                    \
        acc = __builtin_amdgcn_mfma_f32_16x16x32_bf16(ah, bh, acc, 0, 0, 0);\
        acc = __builtin_amdgcn_mfma_f32_16x16x32_bf16(al, bh, acc, 0, 0, 0);\
        acc = __builtin_amdgcn_mfma_f32_16x16x32_bf16(ah, bl, acc, 0, 0, 0);\
    } while (0)

__global__ __launch_bounds__(256, 4) void gnn_mfma(
    const float* __restrict__ x, const unsigned short* __restrict__ wf,
    const float* __restrict__ b0, const float* __restrict__ b1,
    const float* __restrict__ b2, float* __restrict__ out,
    int n_tiles, int stride)
{
    __shared__ __align__(16) unsigned short wlds[N_CHUNKS * 512];  // 22 KB
    // wave-private transpose buffer: [wave][hl][row 16][col 32 + pad 8]
    __shared__ __align__(16) unsigned short hbuf[4][2][16][40];    // 10.25 KB

    const int tid  = threadIdx.x;
    const int wave = tid >> 6;
    const int l    = tid & 63;
    const int r16  = l & 15;
    const int g    = l >> 4;

    // ---- stage weight fragments into LDS once per block ----
    {
        const uint4v* wfv = reinterpret_cast<const uint4v*>(wf);
        uint4v* wl = reinterpret_cast<uint4v*>(wlds);
        for (int gg = tid; gg < WLDS_GRANULES; gg += 256)
            wl[gg] = wfv[gg];
    }
    __syncthreads();   // the only block-wide barrier

    const short8* WL = reinterpret_cast<const short8*>(wlds);

    const float bc0a = b0[r16], bc0b = b0[16 + r16];
    const float bc1a = b1[r16], bc1b = b1[16 + r16];
    const float bc2  = b2[r16];

    const int gw = blockIdx.x * 4 + wave;   // global wave id

    for (int tile = gw; tile < n_tiles; tile += stride) {
        const int nb = tile * 16;

        // -------- layer 0: h0 = relu(x @ W0 + b0), K=128 --------
        f32x4 acc0 = {0.f, 0.f, 0.f, 0.f};
        f32x4 acc1 = {0.f, 0.f, 0.f, 0.f};
        const float* xrow = x + (size_t)(nb + r16) * N_IN + g * 8;

        #pragma unroll
        for (int kc = 0; kc < 4; ++kc) {
            // non-temporal: x is a read-once stream (no reuse anywhere)
            f32x4 xa = __builtin_nontemporal_load(
                reinterpret_cast<const f32x4*>(xrow + kc * 32));
            f32x4 xb = __builtin_nontemporal_load(
                reinterpret_cast<const f32x4*>(xrow + kc * 32 + 4));
            float f[8] = {xa[0], xa[1], xa[2], xa[3], xb[0], xb[1], xb[2], xb[3]};
            uint4v hv, lv;
            #pragma unroll
            for (int p = 0; p < 4; ++p) {
                unsigned u0 = fu(f[2 * p]), u1 = fu(f[2 * p + 1]);
                unsigned h0b = u0 & 0xFFFF0000u, h1b = u1 & 0xFFFF0000u;
                hv[p] = h1b | (u0 >> 16);
                float l0 = f[2 * p] - uf(h0b), l1 = f[2 * p + 1] - uf(h1b);
                lv[p] = (fu(l1) & 0xFFFF0000u) | (fu(l0) >> 16);
            }
            short8 ah = __builtin_bit_cast(short8, hv);
            short8 al = __builtin_bit_cast(short8, lv);
            short8 w0h0 = WL[(kc * 4 + 0) * 64 + l];
            short8 w0l0 = WL[(kc * 4 + 1) * 64 + l];
            short8 w0h1 = WL[(kc * 4 + 2) * 64 + l];
            short8 w0l1 = WL[(kc * 4 + 3) * 64 + l];
            MFMA3(acc0, ah, al, w0h0, w0l0);
            MFMA3(acc1, ah, al, w0h1, w0l1);
        }

        // bias + relu, split hi/lo, wave-private LDS transpose (no barrier)
        #pragma unroll
        for (int i = 0; i < 4; ++i) {
            int row = 4 * g + i;
            float h = fmaxf(acc0[i] + bc0a, 0.f);
            unsigned hb = fu(h) & 0xFFFF0000u;
            hbuf[wave][0][row][r16] = (unsigned short)(hb >> 16);
            hbuf[wave][1][row][r16] = (unsigned short)(fu(h - uf(hb)) >> 16);
            float h2 = fmaxf(acc1[i] + bc0b, 0.f);
            unsigned hb2 = fu(h2) & 0xFFFF0000u;
            hbuf[wave][0][row][16 + r16] = (unsigned short)(hb2 >> 16);
            hbuf[wave][1][row][16 + r16] = (unsigned short)(fu(h2 - uf(hb2)) >> 16);
        }
        short8 h0h = *reinterpret_cast<const short8*>(&hbuf[wave][0][r16][g * 8]);
        short8 h0l = *reinterpret_cast<const short8*>(&hbuf[wave][1][r16][g * 8]);

        // -------- layer 1: h1 = relu(h0 @ W1 + b1), K=32 --------
        f32x4 acc2 = {0.f, 0.f, 0.f, 0.f};
        f32x4 acc3 = {0.f, 0.f, 0.f, 0.f};
        {
            short8 w1h0 = WL[(16 + 0) * 64 + l];
            short8 w1l0 = WL[(16 + 1) * 64 + l];
            short8 w1h1 = WL[(16 + 2) * 64 + l];
            short8 w1l1 = WL[(16 + 3) * 64 + l];
            MFMA3(acc2, h0h, h0l, w1h0, w1l0);
            MFMA3(acc3, h0h, h0l, w1h1, w1l1);
        }
        #pragma unroll
        for (int i = 0; i < 4; ++i) {
            int row = 4 * g + i;
            float h = fmaxf(acc2[i] + bc1a, 0.f);
            unsigned hb = fu(h) & 0xFFFF0000u;
            hbuf[wave][0][row][r16] = (unsigned short)(hb >> 16);
            hbuf[wave][1][row][r16] = (unsigned short)(fu(h - uf(hb)) >> 16);
            float h2 = fmaxf(acc3[i] + bc1b, 0.f);
            unsigned hb2 = fu(h2) & 0xFFFF0000u;
            hbuf[wave][0][row][16 + r16] = (unsigned short)(hb2 >> 16);
            hbuf[wave][1][row][16 + r16] = (unsigned short)(fu(h2 - uf(hb2)) >> 16);
        }
        short8 h1h = *reinterpret_cast<const short8*>(&hbuf[wave][0][r16][g * 8]);
        short8 h1l = *reinterpret_cast<const short8*>(&hbuf[wave][1][r16][g * 8]);

        // -------- layer 2: o = h1 @ W2 + b2, K=32, N=16 --------
        f32x4 accO = {0.f, 0.f, 0.f, 0.f};
        {
            short8 w2h = WL[(20) * 64 + l];
            short8 w2l = WL[(21) * 64 + l];
            MFMA3(accO, h1h, h1l, w2h, w2l);
        }
        #pragma unroll
        for (int i = 0; i < 4; ++i) {
            int row = 4 * g + i;
            // non-temporal: out is write-once, full lines per instruction
            __builtin_nontemporal_store(
                accO[i] + bc2, out + (size_t)(nb + row) * N_OUT + r16);
        }
    }
}

extern "C" void kernel_launch(void* const* d_in, const int* in_sizes, int n_in,
                              void* d_out, int out_size, void* d_ws, size_t ws_size,
                              hipStream_t stream) {
    // setup_inputs() order: x, edge_index, edge_weight, W0, b0, W1, b1, W2, b2
    const float* x  = (const float*)d_in[0];
    const float* W0 = (const float*)d_in[3];
    const float* b0 = (const float*)d_in[4];
    const float* W1 = (const float*)d_in[5];
    const float* b1 = (const float*)d_in[6];
    const float* W2 = (const float*)d_in[7];
    const float* b2 = (const float*)d_in[8];
    float* out = (float*)d_out;
    unsigned short* wf = (unsigned short*)d_ws;   // 22 KB of fragment data

    int n_nodes = in_sizes[0] / N_IN;             // 1,000,000
    int n_tiles = n_nodes / 16;                   // 62,500 (exact)

    split_weights<<<(TOTAL_WF_SHORTS + 255) / 256, 256, 0, stream>>>(W0, W1, W2, wf);

    const int n_blocks = 1024;                    // 4 blocks/CU persistent
    const int n_waves_total = n_blocks * 4;
    gnn_mfma<<<dim3(n_blocks), dim3(256), 0, stream>>>(
        x, wf, b0, b1, b2, out, n_tiles, n_waves_total);
}